// Round 4
// baseline (249.194 us; speedup 1.0000x reference)
//
#include <hip/hip_runtime.h>

// VQ-VAE vector quantizer, MI355X (gfx950).
//   inputs : z (8,256,16,16,16) fp32, codebook (1024,256) fp32
//   output : quant (8,256,16,16,16) ++ idx (8,16,16,16) ++ loss (1), fp32 flat
//
// Round 10: r6's proven Phase C skeleton (TOK_BLK=64, reg-round-trip staging,
//   wave-private candidate lists, 2 blocks/CU) + explicit register prefetch:
//   stage s+1's 8 uint4 loads issue BEFORE stage-s compute (pure HIP T14
//   async-split; no asm, no sched_barrier -- compiler keeps freedom).
//   Staging window now only 8 ds_write_b128 + 2 barriers; global latency
//   hides under 32 MFMAs + filter. Stage-0 prefetch hides under Sz/A-frags.
//   Keeps verified r7/r8 wins: 64-lane exact Sz, parallel prep, fused loss,
//   float4 Phase D/E gathers.
//   Empirical law rounds 6-9: fastest Phase C keeps stage loads in VGPRs
//   (r6 133us) vs global_load_lds (142) / asm-async (152) / L2-direct (152).

#define K_CODES 1024
#define DIM 256
#define N_TOK 32768
#define SPATIAL 4096
#define TOK_BLK 64
#define NBLK (N_TOK / TOK_BLK)
#define CAP 28
#define MARGIN 1e-3f

typedef __attribute__((ext_vector_type(8))) short short8;
typedef __attribute__((ext_vector_type(4))) float float4v;

// ws layout in floats
#define WS_LOSS 0
#define WS_CNT 8      // unsigned completion counter (byte 32)
#define WS_E2 16      // 1024 floats: Se[k] (np pairwise)
#define WS_EB 2048    // 262144 bf16: codebook, B-fragment order

#define O_IDX (8 * DIM * SPATIAL)  // 8388608
#define O_LOSS (O_IDX + N_TOK)     // 8421376

__device__ __forceinline__ short f2bf(float v) {  // RTNE fp32->bf16 bits
  unsigned u = __float_as_uint(v);
  u = (u + 0x7fffu + ((u >> 16) & 1u)) >> 16;
  return (short)u;
}

// prep: Se[k] np-pairwise (exact order, parallelized); codebook -> bf16 in
// MFMA B-fragment order, 16B chunk stores.  (verified rounds 7-9)
__global__ __launch_bounds__(256) void prep_kernel(const float* __restrict__ e,
                                                   float* __restrict__ ws) {
  __shared__ float sq[DIM];
  __shared__ __align__(16) short sbf[DIM];
  __shared__ float chv[16];
  int k = blockIdx.x, d = threadIdx.x;
  float v = e[k * DIM + d];
  sbf[d] = f2bf(v);
  sq[d] = __fmul_rn(v, v);
  __syncthreads();
  if (d < 32) {  // 16B chunk stores of the fragment layout
    int f = d >> 2, q = d & 3;
    int stage = k >> 6, ct = (k >> 4) & 3, nn = k & 15;
    short8 chunk = *(const short8*)(sbf + f * 32 + q * 8);
    int off8 = ((stage * 4 + ct) * 8 + f) * 64 + q * 16 + nn;
    ((short8*)(ws + WS_EB))[off8] = chunk;
  }
  if (d < 16) {  // chain (blk=d>>3, j=d&7): exact np serial order i=0..15
    int blkb = d >> 3, j = d & 7;
    const float* x = sq + blkb * 128;
    float c = x[j];
#pragma unroll
    for (int i = 1; i < 16; i++) c = __fadd_rn(c, x[i * 8 + j]);
    chv[d] = c;
  }
  __syncthreads();
  if (d == 0) {  // exact np_pairwise128 combine tree, then blk0+blk1
    float a0 = __fadd_rn(__fadd_rn(chv[0], chv[1]), __fadd_rn(chv[2], chv[3]));
    float a1 = __fadd_rn(__fadd_rn(chv[4], chv[5]), __fadd_rn(chv[6], chv[7]));
    float resA = __fadd_rn(a0, a1);
    float b0 = __fadd_rn(__fadd_rn(chv[8], chv[9]), __fadd_rn(chv[10], chv[11]));
    float b1 = __fadd_rn(__fadd_rn(chv[12], chv[13]), __fadd_rn(chv[14], chv[15]));
    float resB = __fadd_rn(b0, b1);
    ws[WS_E2 + k] = __fadd_rn(resA, resB);
    if (k == 0) {
      ws[WS_LOSS] = 0.f;
      ((unsigned*)ws)[WS_CNT] = 0u;
    }
  }
}

__global__ __launch_bounds__(256, 2) void main_kernel(const float* __restrict__ z,
                                                      const float* __restrict__ e,
                                                      float* __restrict__ ws,
                                                      float* __restrict__ out) {
  __shared__ __align__(16) short Bst[64 * 256];  // 32 KB, fragment order
  __shared__ unsigned short cand[TOK_BLK][CAP];
  __shared__ float cands[TOK_BLK][CAP];
  __shared__ float aminv[TOK_BLK];
  __shared__ int cnt[TOK_BLK];
  __shared__ float Szs[TOK_BLK];
  __shared__ int mini_sh[TOK_BLK];
  __shared__ float red[4];

  int tid = threadIdx.x, w = tid >> 6, lane = tid & 63;
  int quad = lane >> 4, nn = lane & 15;
  int n0 = blockIdx.x * TOK_BLK;
  int b = n0 >> 12, s0 = n0 & 4095;
  const float* zb = z + (size_t)b * DIM * SPATIAL + s0;
  const float* Se = ws + WS_E2;
  const uint4* eBg = (const uint4*)(ws + WS_EB);
  if (tid < TOK_BLK) cnt[tid] = 0;

  // ---- stage-0 prefetch into regs; latency hides under Sz + A-frags ----
  uint4 pf[8];
#pragma unroll
  for (int i = 0; i < 8; i++) pf[i] = eBg[i * 256 + tid];

  // ---- Sz (exact np pairwise), all 64 lanes: lane (quad,nn) runs the 4
  //      chains c = quad*4+t of token w*16+nn; shfl merges replicate the
  //      exact __fadd_rn tree (verified rounds 7-8) ----
  {
    const float* zp = zb + w * 16 + nn;
    float r[4];
#pragma unroll
    for (int t = 0; t < 4; t++) {
      int c = quad * 4 + t, blkb = c >> 3, j = c & 7;
      float v0 = zp[(size_t)(blkb * 128 + j) * SPATIAL];
      r[t] = __fmul_rn(v0, v0);
      for (int i = 1; i < 16; i++) {
        float vv = zp[(size_t)(blkb * 128 + i * 8 + j) * SPATIAL];
        r[t] = __fadd_rn(r[t], __fmul_rn(vv, vv));
      }
    }
    float half = __fadd_rn(__fadd_rn(r[0], r[1]), __fadd_rn(r[2], r[3]));
    float other = __shfl_xor(half, 16);
    float resb = __fadd_rn(half, other);   // valid order on quad 0
    float res_o = __shfl_xor(resb, 32);
    float total = __fadd_rn(resb, res_o);  // valid order on quad 0
    if (quad == 0) Szs[w * 16 + nn] = total;
  }

  // ---- A fragments (z -> bf16) in registers: token m = w*16+nn,
  //      frag f holds k-dim d = f*32 + quad*8 + j ----
  int tokA = w * 16 + nn;
  short8 A[8];
#pragma unroll
  for (int f = 0; f < 8; f++) {
    short8 a;
#pragma unroll
    for (int j = 0; j < 8; j++) {
      int d = f * 32 + quad * 8 + j;
      a[j] = f2bf(zb[(size_t)d * SPATIAL + tokA]);
    }
    A[f] = a;
  }

  // ---- Phase C: MFMA filter over 16 stages of 64 codes.
  //      Stage window = 8 ds_write_b128 only; s+1 loads issued before
  //      compute, drained by next iteration's first __syncthreads. ----
  float thr[4] = {3.4e38f, 3.4e38f, 3.4e38f, 3.4e38f};
  for (int stage = 0; stage < 16; stage++) {
    __syncthreads();  // prior-stage LDS reads done; drains pf loads (vmcnt 0)
#pragma unroll
    for (int i = 0; i < 8; i++)
      ((uint4*)Bst)[i * 256 + tid] = pf[i];
    __syncthreads();  // data ready for all waves

    if (stage < 15) {  // prefetch next stage; flies under the MFMAs below
#pragma unroll
      for (int i = 0; i < 8; i++)
        pf[i] = eBg[(size_t)(stage + 1) * 2048 + i * 256 + tid];
    }

    for (int ct = 0; ct < 4; ct++) {
      int kbase = stage * 64 + ct * 16;
      float4v C = {0.f, 0.f, 0.f, 0.f};
      const short8* Bp = (const short8*)Bst + ct * 8 * 64;
#pragma unroll
      for (int f = 0; f < 8; f++) {
        short8 Bf = Bp[f * 64 + lane];  // ds_read_b128, conflict-free
        C = __builtin_amdgcn_mfma_f32_16x16x32_bf16(A[f], Bf, C, 0, 0, 0);
      }
      float SeK = Se[kbase + nn];  // col = code = nn
      float sv[4];
      bool pr[4];
#pragma unroll
      for (int r = 0; r < 4; r++) {  // row = token = quad*4 + r
        float s = fmaf(-2.f, C[r], SeK);
        float m = s;  // rowmin across the 16 lanes of this row
        m = fminf(m, __shfl_xor(m, 1, 16));
        m = fminf(m, __shfl_xor(m, 2, 16));
        m = fminf(m, __shfl_xor(m, 4, 16));
        m = fminf(m, __shfl_xor(m, 8, 16));
        thr[r] = fminf(thr[r], m);
        sv[r] = s;
        pr[r] = s < thr[r] + MARGIN;
      }
      if (__ballot(pr[0] | pr[1] | pr[2] | pr[3])) {  // rare path
#pragma unroll
        for (int r = 0; r < 4; r++) {
          unsigned long long bl = __ballot(pr[r]);
          unsigned grp = (unsigned)((bl >> (quad * 16)) & 0xffffULL);
          if (grp) {
            int tb = w * 16 + quad * 4 + r;
            int base = cnt[tb];
            if (pr[r]) {
              int pos = base + __popc(grp & ((1u << nn) - 1u));
              if (pos < CAP) {
                cand[tb][pos] = (unsigned short)(kbase + nn);
                cands[tb][pos] = sv[r];
              }
            }
            if (nn == 0) cnt[tb] = base + __popc(grp);
          }
        }
      }
    }
  }
  // publish per-token final approx min (for recheck skip filter)
#pragma unroll
  for (int r = 0; r < 4; r++)
    if (nn == 0) aminv[w * 16 + quad * 4 + r] = thr[r];

  // ---- Phase D: exact recheck (wave-private tokens; no barrier needed).
  //      e-row read as float4; fmaf chain exact ascending d (verified r8). ----
  int tb = w * 16 + nn;  // lane handles token nn, candidate slots quad::4
  int cc = cnt[tb];
  int cl = cc < CAP ? cc : CAP;
  float bestD = 3.4e38f;
  int bestk = 0x7fffffff;
  {
    const float* zp = zb + tb;
    float amin = aminv[tb], Szn = Szs[tb];
    for (int c = quad; c < cl; c += 4) {
      if (cands[tb][c] >= amin + MARGIN) continue;  // pruned
      int k = cand[tb][c];
      const float* er = e + (size_t)k * DIM;
      float acc = 0.f;
#pragma unroll 4
      for (int dd = 0; dd < DIM; dd += 4) {
        float4 e4 = *(const float4*)(er + dd);
        acc = fmaf(zp[(size_t)(dd + 0) * SPATIAL], e4.x, acc);
        acc = fmaf(zp[(size_t)(dd + 1) * SPATIAL], e4.y, acc);
        acc = fmaf(zp[(size_t)(dd + 2) * SPATIAL], e4.z, acc);
        acc = fmaf(zp[(size_t)(dd + 3) * SPATIAL], e4.w, acc);
      }
      float D = __fsub_rn(__fadd_rn(Szn, Se[k]), __fmul_rn(2.f, acc));
      if (D < bestD || (D == bestD && k < bestk)) { bestD = D; bestk = k; }
    }
  }
#pragma unroll
  for (int off = 32; off >= 16; off >>= 1) {  // merge the 4 quads per token
    float oD = __shfl_down(bestD, off);
    int ok = __shfl_down(bestk, off);
    if (oD < bestD || (oD == bestD && ok < bestk)) { bestD = oD; bestk = ok; }
  }
  if (lane < 16 && cnt[w * 16 + lane] <= CAP) {
    mini_sh[w * 16 + lane] = bestk;
    out[O_IDX + n0 + w * 16 + lane] = (float)bestk;
  }
  // overflow tokens: exact full scan by the whole wave (deterministic)
  for (int t = 0; t < 16; t++) {
    int tb2 = w * 16 + t;
    if (cnt[tb2] > CAP) {
      const float* zq = zb + tb2;
      float Szn = Szs[tb2];
      float bD = 3.4e38f;
      int bk = 0x7fffffff;
      for (int k = lane; k < K_CODES; k += 64) {
        const float* er = e + (size_t)k * DIM;
        float acc = 0.f;
#pragma unroll 4
        for (int dd = 0; dd < DIM; dd += 4) {
          float4 e4 = *(const float4*)(er + dd);
          acc = fmaf(zq[(size_t)(dd + 0) * SPATIAL], e4.x, acc);
          acc = fmaf(zq[(size_t)(dd + 1) * SPATIAL], e4.y, acc);
          acc = fmaf(zq[(size_t)(dd + 2) * SPATIAL], e4.z, acc);
          acc = fmaf(zq[(size_t)(dd + 3) * SPATIAL], e4.w, acc);
        }
        float D = __fsub_rn(__fadd_rn(Szn, Se[k]), __fmul_rn(2.f, acc));
        if (D < bD || (D == bD && k < bk)) { bD = D; bk = k; }
      }
#pragma unroll
      for (int m = 1; m < 64; m <<= 1) {
        float oD = __shfl_xor(bD, m);
        int ok = __shfl_xor(bk, m);
        if (oD < bD || (oD == bD && ok < bk)) { bD = oD; bk = ok; }
      }
      if (lane == 0) {
        mini_sh[tb2] = bk;
        out[O_IDX + n0 + tb2] = (float)bk;
      }
    }
  }
  __syncthreads();

  // ---- Phase E: quant gather + store + loss; e-row read as float4 ----
  int mten = mini_sh[lane];  // lane = token
  const float* erow = e + (size_t)mten * DIM;
  float* op = out + (size_t)b * DIM * SPATIAL + s0;
  float sumsq = 0.f;
#pragma unroll 4
  for (int i4 = 0; i4 < 64; i4 += 4) {
    int d = w * 64 + i4;  // wave-uniform d, 16B-aligned
    float4 v4 = *(const float4*)(erow + d);
#pragma unroll
    for (int m = 0; m < 4; m++) {
      float v = (m == 0) ? v4.x : (m == 1) ? v4.y : (m == 2) ? v4.z : v4.w;
      float zv = zb[(size_t)(d + m) * SPATIAL + lane];
      float df = __fsub_rn(v, zv);
      sumsq = fmaf(df, df, sumsq);
      op[(size_t)(d + m) * SPATIAL + lane] = v;  // coalesced 64-wide store
    }
  }
#pragma unroll
  for (int o = 32; o > 0; o >>= 1) sumsq += __shfl_down(sumsq, o, 64);
  if (lane == 0) red[w] = sumsq;
  __syncthreads();
  if (tid == 0) {
    atomicAdd(ws + WS_LOSS, red[0] + red[1] + red[2] + red[3]);
    __threadfence();  // loss add globally visible before counter bump
    unsigned t = atomicAdd((unsigned*)ws + WS_CNT, 1u);
    if (t == NBLK - 1) {  // last block publishes loss
      float total = atomicAdd(ws + WS_LOSS, 0.f);  // device-scope read
      out[O_LOSS] = 1.25f * total / 8388608.f;
    }
  }
}

extern "C" void kernel_launch(void* const* d_in, const int* in_sizes, int n_in,
                              void* d_out, int out_size, void* d_ws, size_t ws_size,
                              hipStream_t stream) {
  const float* z = (const float*)d_in[0];
  const float* e = (const float*)d_in[1];
  float* ws = (float*)d_ws;
  float* out = (float*)d_out;

  prep_kernel<<<K_CODES, 256, 0, stream>>>(e, ws);
  main_kernel<<<NBLK, 256, 0, stream>>>(z, e, ws, out);
}

// Round 5
// 203.365 us; speedup vs baseline: 1.2254x; 1.2254x over previous
//
#include <hip/hip_runtime.h>

// VQ-VAE vector quantizer, MI355X (gfx950).
//   inputs : z (8,256,16,16,16) fp32, codebook (1024,256) fp32
//   output : quant (8,256,16,16,16) ++ idx (8,16,16,16) ++ loss (1), fp32 flat
//
// Round 11: r6's proven Phase C staging (reg round-trip, loads consumed
//   inside the stage window -- the only form the compiler pipelines well;
//   cross-barrier prefetch spilled to scratch in r10: WRITE 33->155MB) but
//   with 8 waves/block = (token-group g x codebook-half kh): 512 threads,
//   grid 512 -> 16 waves/CU (was 8 in every prior round). Same total work;
//   2x waves to hide the latency that has every pipe <21% busy.
//   Shared candidate lists -> LDS atomicAdd append (r9-verified order-
//   independent); per-half aminv min'd in D (r9-verified superset safety).
//   Sz split by 128-dim block across the kh pair, exact np __fadd_rn tree
//   (r8-verified merges), halves combined blk0+blk1 in D (bit-exact).
//   Keeps: parallel prep, fused loss, float4 D/E gathers.

#define K_CODES 1024
#define DIM 256
#define N_TOK 32768
#define SPATIAL 4096
#define TOK_BLK 64
#define NBLK (N_TOK / TOK_BLK)
#define CAP 28
#define MARGIN 1e-3f

typedef __attribute__((ext_vector_type(8))) short short8;
typedef __attribute__((ext_vector_type(4))) float float4v;

// ws layout in floats
#define WS_LOSS 0
#define WS_CNT 8      // unsigned completion counter (byte 32)
#define WS_E2 16      // 1024 floats: Se[k] (np pairwise)
#define WS_EB 2048    // 262144 bf16: codebook, B-fragment order

#define O_IDX (8 * DIM * SPATIAL)  // 8388608
#define O_LOSS (O_IDX + N_TOK)     // 8421376

__device__ __forceinline__ short f2bf(float v) {  // RTNE fp32->bf16 bits
  unsigned u = __float_as_uint(v);
  u = (u + 0x7fffu + ((u >> 16) & 1u)) >> 16;
  return (short)u;
}

// prep: Se[k] np-pairwise (exact order, parallelized); codebook -> bf16 in
// MFMA B-fragment order, 16B chunk stores.  (verified rounds 7-10)
__global__ __launch_bounds__(256) void prep_kernel(const float* __restrict__ e,
                                                   float* __restrict__ ws) {
  __shared__ float sq[DIM];
  __shared__ __align__(16) short sbf[DIM];
  __shared__ float chv[16];
  int k = blockIdx.x, d = threadIdx.x;
  float v = e[k * DIM + d];
  sbf[d] = f2bf(v);
  sq[d] = __fmul_rn(v, v);
  __syncthreads();
  if (d < 32) {  // 16B chunk stores of the fragment layout
    int f = d >> 2, q = d & 3;
    int stage = k >> 6, ct = (k >> 4) & 3, nn = k & 15;
    short8 chunk = *(const short8*)(sbf + f * 32 + q * 8);
    int off8 = ((stage * 4 + ct) * 8 + f) * 64 + q * 16 + nn;
    ((short8*)(ws + WS_EB))[off8] = chunk;
  }
  if (d < 16) {  // chain (blk=d>>3, j=d&7): exact np serial order i=0..15
    int blkb = d >> 3, j = d & 7;
    const float* x = sq + blkb * 128;
    float c = x[j];
#pragma unroll
    for (int i = 1; i < 16; i++) c = __fadd_rn(c, x[i * 8 + j]);
    chv[d] = c;
  }
  __syncthreads();
  if (d == 0) {  // exact np_pairwise128 combine tree, then blk0+blk1
    float a0 = __fadd_rn(__fadd_rn(chv[0], chv[1]), __fadd_rn(chv[2], chv[3]));
    float a1 = __fadd_rn(__fadd_rn(chv[4], chv[5]), __fadd_rn(chv[6], chv[7]));
    float resA = __fadd_rn(a0, a1);
    float b0 = __fadd_rn(__fadd_rn(chv[8], chv[9]), __fadd_rn(chv[10], chv[11]));
    float b1 = __fadd_rn(__fadd_rn(chv[12], chv[13]), __fadd_rn(chv[14], chv[15]));
    float resB = __fadd_rn(b0, b1);
    ws[WS_E2 + k] = __fadd_rn(resA, resB);
    if (k == 0) {
      ws[WS_LOSS] = 0.f;
      ((unsigned*)ws)[WS_CNT] = 0u;
    }
  }
}

__global__ __launch_bounds__(512, 4) void main_kernel(const float* __restrict__ z,
                                                      const float* __restrict__ e,
                                                      float* __restrict__ ws,
                                                      float* __restrict__ out) {
  __shared__ __align__(16) short Bst[64 * 256];  // 32 KB, fragment order
  __shared__ unsigned short cand[TOK_BLK][CAP];
  __shared__ float cands[TOK_BLK][CAP];
  __shared__ float aminv[2][TOK_BLK];  // per-k-half final approx min
  __shared__ int cnt[TOK_BLK];
  __shared__ float Szp[2][TOK_BLK];    // per-128-dim-block Sz partials
  __shared__ int mini_sh[TOK_BLK];
  __shared__ float red[8];

  int tid = threadIdx.x, w = tid >> 6, lane = tid & 63;
  int quad = lane >> 4, nn = lane & 15;
  int g = w & 3, kh = w >> 2;  // token group (16 tokens), codebook half
  int n0 = blockIdx.x * TOK_BLK;
  int b = n0 >> 12, s0 = n0 & 4095;
  const float* zb = z + (size_t)b * DIM * SPATIAL + s0;
  const float* Se = ws + WS_E2;
  const uint4* eBg = (const uint4*)(ws + WS_EB);
  if (tid < TOK_BLK) cnt[tid] = 0;

  // ---- Sz partial (exact np pairwise): wave kh does dim-block kh (128 d)
  //      for its 16 tokens. Lane (quad,nn): chains j = quad*2 + {0,1} of
  //      token g*16+nn. Merge tree = exact np pairing (r8-verified):
  //      p=(c2q+c2q+1); xor16 -> (p0+p1)|(p2+p3); xor32 -> blk result. ----
  {
    const float* zp = zb + g * 16 + nn;
    float r0, r1;
    {
      int j0 = quad * 2;
      float v0 = zp[(size_t)(kh * 128 + j0) * SPATIAL];
      float v1 = zp[(size_t)(kh * 128 + j0 + 1) * SPATIAL];
      r0 = __fmul_rn(v0, v0);
      r1 = __fmul_rn(v1, v1);
      for (int i = 1; i < 16; i++) {
        v0 = zp[(size_t)(kh * 128 + i * 8 + j0) * SPATIAL];
        v1 = zp[(size_t)(kh * 128 + i * 8 + j0 + 1) * SPATIAL];
        r0 = __fadd_rn(r0, __fmul_rn(v0, v0));
        r1 = __fadd_rn(r1, __fmul_rn(v1, v1));
      }
    }
    float p = __fadd_rn(r0, r1);                    // (c_{2q} + c_{2q+1})
    float s1 = __fadd_rn(p, __shfl_xor(p, 16));     // (p0+p1) | (p2+p3)
    float s2 = __fadd_rn(s1, __shfl_xor(s1, 32));   // np_pairwise128 result
    if (quad == 0) Szp[kh][g * 16 + nn] = s2;
  }

  // ---- A fragments (z -> bf16) in registers: token m = g*16+nn,
  //      frag f holds k-dim d = f*32 + quad*8 + j. (kh pair duplicates;
  //      cached reads.) ----
  int tokA = g * 16 + nn;
  short8 A[8];
#pragma unroll
  for (int f = 0; f < 8; f++) {
    short8 a;
#pragma unroll
    for (int j = 0; j < 8; j++) {
      int d = f * 32 + quad * 8 + j;
      a[j] = f2bf(zb[(size_t)d * SPATIAL + tokA]);
    }
    A[f] = a;
  }

  // ---- Phase C: MFMA filter over 16 stages of 64 codes. r6 staging form
  //      (loads consumed inside the window -- compiler pipelines it).
  //      Wave (g,kh) computes ct = kh*2+{0,1} each stage: 16 MFMA. ----
  float thr[4] = {3.4e38f, 3.4e38f, 3.4e38f, 3.4e38f};
  for (int stage = 0; stage < 16; stage++) {
    __syncthreads();  // prior-stage LDS reads done (also orders cnt=0, Szp)
#pragma unroll
    for (int i = 0; i < 4; i++)  // 32 KB via 512 threads: reg round-trip
      ((uint4*)Bst)[i * 512 + tid] = eBg[(size_t)stage * 2048 + i * 512 + tid];
    __syncthreads();  // data ready

    for (int ctl = 0; ctl < 2; ctl++) {
      int ct = kh * 2 + ctl;
      int kbase = stage * 64 + ct * 16;
      float4v C = {0.f, 0.f, 0.f, 0.f};
      const short8* Bp = (const short8*)Bst + ct * 8 * 64;
#pragma unroll
      for (int f = 0; f < 8; f++) {
        short8 Bf = Bp[f * 64 + lane];  // ds_read_b128, conflict-free
        C = __builtin_amdgcn_mfma_f32_16x16x32_bf16(A[f], Bf, C, 0, 0, 0);
      }
      float SeK = Se[kbase + nn];  // col = code = nn
      float sv[4];
      bool pr[4];
#pragma unroll
      for (int r = 0; r < 4; r++) {  // row = token = quad*4 + r
        float s = fmaf(-2.f, C[r], SeK);
        float m = s;  // rowmin across the 16 lanes of this row
        m = fminf(m, __shfl_xor(m, 1, 16));
        m = fminf(m, __shfl_xor(m, 2, 16));
        m = fminf(m, __shfl_xor(m, 4, 16));
        m = fminf(m, __shfl_xor(m, 8, 16));
        thr[r] = fminf(thr[r], m);
        sv[r] = s;
        pr[r] = s < thr[r] + MARGIN;
      }
      if (__ballot(pr[0] | pr[1] | pr[2] | pr[3])) {  // rare path
#pragma unroll
        for (int r = 0; r < 4; r++) {
          unsigned long long bl = __ballot(pr[r]);
          unsigned grp = (unsigned)((bl >> (quad * 16)) & 0xffffULL);
          if (grp) {  // quad-uniform
            int tb = g * 16 + quad * 4 + r;
            int base = 0;
            if (nn == 0) base = atomicAdd(&cnt[tb], __popc(grp));
            base = __shfl(base, quad * 16);  // broadcast from quad's lane 0
            if (pr[r]) {
              int pos = base + __popc(grp & ((1u << nn) - 1u));
              if (pos < CAP) {
                cand[tb][pos] = (unsigned short)(kbase + nn);
                cands[tb][pos] = sv[r];
              }
            }
          }
        }
      }
    }
  }
  // publish per-(token, k-half) final approx min
#pragma unroll
  for (int r = 0; r < 4; r++)
    if (nn == 0) aminv[kh][g * 16 + quad * 4 + r] = thr[r];
  __syncthreads();  // candidates + aminv + Szp ready across the kh pairs

  // ---- Phase D: exact recheck. Wave w owns tokens w*8..w*8+7; lane =
  //      (token tl, oct); candidate slots oct::8 (r9-verified mapping).
  //      Lex-min (D,k) over the set is append-order-independent. ----
  int tl = lane >> 3, oct = lane & 7;
  int tb = w * 8 + tl;
  int cc = cnt[tb];
  int cl = cc < CAP ? cc : CAP;
  float bestD = 3.4e38f;
  int bestk = 0x7fffffff;
  float SznT = __fadd_rn(Szp[0][tb], Szp[1][tb]);  // exact: blk0 + blk1
  {
    const float* zp = zb + tb;
    float amin = fminf(aminv[0][tb], aminv[1][tb]);
    for (int c = oct; c < cl; c += 8) {
      if (cands[tb][c] >= amin + MARGIN) continue;  // pruned
      int k = cand[tb][c];
      const float* er = e + (size_t)k * DIM;
      float acc = 0.f;
#pragma unroll 4
      for (int dd = 0; dd < DIM; dd += 4) {
        float4 e4 = *(const float4*)(er + dd);
        acc = fmaf(zp[(size_t)(dd + 0) * SPATIAL], e4.x, acc);
        acc = fmaf(zp[(size_t)(dd + 1) * SPATIAL], e4.y, acc);
        acc = fmaf(zp[(size_t)(dd + 2) * SPATIAL], e4.z, acc);
        acc = fmaf(zp[(size_t)(dd + 3) * SPATIAL], e4.w, acc);
      }
      float D = __fsub_rn(__fadd_rn(SznT, Se[k]), __fmul_rn(2.f, acc));
      if (D < bestD || (D == bestD && k < bestk)) { bestD = D; bestk = k; }
    }
  }
#pragma unroll
  for (int off = 4; off >= 1; off >>= 1) {  // merge the 8 lanes per token
    float oD = __shfl_down(bestD, off, 8);
    int ok = __shfl_down(bestk, off, 8);
    if (oD < bestD || (oD == bestD && ok < bestk)) { bestD = oD; bestk = ok; }
  }
  if (oct == 0 && cc <= CAP) {
    mini_sh[tb] = bestk;
    out[O_IDX + n0 + tb] = (float)bestk;
  }
  // overflow tokens: exact full scan by the whole wave (deterministic)
  for (int t = 0; t < 8; t++) {
    int tb2 = w * 8 + t;
    if (cnt[tb2] > CAP) {
      const float* zq = zb + tb2;
      float Szn = __fadd_rn(Szp[0][tb2], Szp[1][tb2]);
      float bD = 3.4e38f;
      int bk = 0x7fffffff;
      for (int k = lane; k < K_CODES; k += 64) {
        const float* er = e + (size_t)k * DIM;
        float acc = 0.f;
#pragma unroll 4
        for (int dd = 0; dd < DIM; dd += 4) {
          float4 e4 = *(const float4*)(er + dd);
          acc = fmaf(zq[(size_t)(dd + 0) * SPATIAL], e4.x, acc);
          acc = fmaf(zq[(size_t)(dd + 1) * SPATIAL], e4.y, acc);
          acc = fmaf(zq[(size_t)(dd + 2) * SPATIAL], e4.z, acc);
          acc = fmaf(zq[(size_t)(dd + 3) * SPATIAL], e4.w, acc);
        }
        float D = __fsub_rn(__fadd_rn(Szn, Se[k]), __fmul_rn(2.f, acc));
        if (D < bD || (D == bD && k < bk)) { bD = D; bk = k; }
      }
#pragma unroll
      for (int m = 1; m < 64; m <<= 1) {
        float oD = __shfl_xor(bD, m);
        int ok = __shfl_xor(bk, m);
        if (oD < bD || (oD == bD && ok < bk)) { bD = oD; bk = ok; }
      }
      if (lane == 0) {
        mini_sh[tb2] = bk;
        out[O_IDX + n0 + tb2] = (float)bk;
      }
    }
  }
  __syncthreads();

  // ---- Phase E: quant gather + store + loss. lane = token (0..63);
  //      wave w covers dims [w*32, w*32+32); e-row read as float4 ----
  int mten = mini_sh[lane];
  const float* erow = e + (size_t)mten * DIM;
  float* op = out + (size_t)b * DIM * SPATIAL + s0;
  float sumsq = 0.f;
#pragma unroll 2
  for (int i4 = 0; i4 < 32; i4 += 4) {
    int d = w * 32 + i4;  // wave-uniform d, 16B-aligned
    float4 v4 = *(const float4*)(erow + d);
#pragma unroll
    for (int m = 0; m < 4; m++) {
      float v = (m == 0) ? v4.x : (m == 1) ? v4.y : (m == 2) ? v4.z : v4.w;
      float zv = zb[(size_t)(d + m) * SPATIAL + lane];
      float df = __fsub_rn(v, zv);
      sumsq = fmaf(df, df, sumsq);
      op[(size_t)(d + m) * SPATIAL + lane] = v;  // coalesced 64-wide store
    }
  }
#pragma unroll
  for (int o = 32; o > 0; o >>= 1) sumsq += __shfl_down(sumsq, o, 64);
  if (lane == 0) red[w] = sumsq;
  __syncthreads();
  if (tid == 0) {
    float rs = ((red[0] + red[1]) + (red[2] + red[3])) +
               ((red[4] + red[5]) + (red[6] + red[7]));
    atomicAdd(ws + WS_LOSS, rs);
    __threadfence();  // loss add globally visible before counter bump
    unsigned t = atomicAdd((unsigned*)ws + WS_CNT, 1u);
    if (t == NBLK - 1) {  // last block publishes loss
      float total = atomicAdd(ws + WS_LOSS, 0.f);  // device-scope read
      out[O_LOSS] = 1.25f * total / 8388608.f;
    }
  }
}

extern "C" void kernel_launch(void* const* d_in, const int* in_sizes, int n_in,
                              void* d_out, int out_size, void* d_ws, size_t ws_size,
                              hipStream_t stream) {
  const float* z = (const float*)d_in[0];
  const float* e = (const float*)d_in[1];
  float* ws = (float*)d_ws;
  float* out = (float*)d_out;

  prep_kernel<<<K_CODES, 256, 0, stream>>>(e, ws);
  main_kernel<<<NBLK, 512, 0, stream>>>(z, e, ws, out);
}